// Round 3
// baseline (872.625 us; speedup 1.0000x reference)
//
#include <hip/hip_runtime.h>
#include <math.h>

constexpr int D_TOT = 97;
constexpr int K_POOL = 30;
constexpr float NEG = -3.0e38f;
constexpr int BSHIFT = 11;                 // 2048 nodes per bucket
constexpr int MAXB = 128;                  // max buckets (n < 262144)

// ---------------- bucket count + degree (one read of dst) ----------------
__global__ __launch_bounds__(256) void k_bcount(const int* __restrict__ dst, int E,
                                                int* __restrict__ deg,
                                                int* __restrict__ bucketcnt, int B) {
    __shared__ int h[MAXB];
    int t = threadIdx.x;
    if (t < MAXB) h[t] = 0;
    __syncthreads();
    int e0 = blockIdx.x * 4096;
    int e1 = min(e0 + 4096, E);
    for (int i = e0 + t; i < e1; i += 256) {
        int d = dst[i];
        atomicAdd(&deg[d], 1);
        atomicAdd(&h[d >> BSHIFT], 1);
    }
    __syncthreads();
    for (int i = t; i < B; i += 256)
        if (h[i]) atomicAdd(&bucketcnt[i], h[i]);
}

// ---------------- bucket exclusive scan ----------------
__global__ void k_bscan(const int* __restrict__ cnt, int* __restrict__ bstart,
                        int* __restrict__ bcursor, int B, int E) {
    __shared__ int s[MAXB];
    int t = threadIdx.x;          // blockDim = 128
    int mine = (t < B) ? cnt[t] : 0;
    s[t] = mine;
    __syncthreads();
    for (int off = 1; off < MAXB; off <<= 1) {
        int add = (t >= off) ? s[t - off] : 0;
        __syncthreads();
        s[t] += add;
        __syncthreads();
    }
    if (t < B) { int ex = s[t] - mine; bstart[t] = ex; bcursor[t] = ex; }
    if (t == 0) bstart[B] = E;
}

// ---------------- phase 1: partition edges into bucket-contiguous packed array ----------------
__global__ __launch_bounds__(256) void k_part(const int* __restrict__ src,
                                              const int* __restrict__ dst, int E, int B,
                                              int* __restrict__ bcursor,
                                              unsigned* __restrict__ bpk) {
    __shared__ int s_src[4096];
    __shared__ int s_dst[4096];
    __shared__ int hist[MAXB];
    __shared__ int base[MAXB];
    int t = threadIdx.x;
    int e0 = blockIdx.x * 4096;
    int cnt = min(4096, E - e0);
    if (t < MAXB) hist[t] = 0;
    __syncthreads();
    for (int i = t; i < cnt; i += 256) {
        int d = dst[e0 + i];
        s_src[i] = src[e0 + i];
        s_dst[i] = d;
        atomicAdd(&hist[d >> BSHIFT], 1);
    }
    __syncthreads();
    for (int i = t; i < B; i += 256) {
        int hh = hist[i];
        base[i] = hh ? atomicAdd(&bcursor[i], hh) : 0;
        hist[i] = 0;
    }
    __syncthreads();
    for (int i = t; i < cnt; i += 256) {
        int d = s_dst[i];
        int b = d >> BSHIFT;
        int off = atomicAdd(&hist[b], 1);
        bpk[base[b] + off] = ((unsigned)(d & ((1 << BSHIFT) - 1)) << 18) | (unsigned)s_src[i];
    }
}

// ---------------- 2-level exclusive scan of deg -> rowstart ----------------
__global__ void k_scan1(const int* __restrict__ deg, int n,
                        int* __restrict__ rowstart, int* __restrict__ bsum) {
    __shared__ int s[1024];
    int t = threadIdx.x;
    int i = blockIdx.x * 1024 + t;
    int mine = (i < n) ? deg[i] : 0;
    s[t] = mine;
    __syncthreads();
    for (int off = 1; off < 1024; off <<= 1) {
        int add = (t >= off) ? s[t - off] : 0;
        __syncthreads();
        s[t] += add;
        __syncthreads();
    }
    if (i < n) rowstart[i] = s[t] - mine;
    if (t == 1023) bsum[blockIdx.x] = s[1023];
}

__global__ void k_scan2(const int* __restrict__ in, int* __restrict__ outx, int m) {
    __shared__ int s[1024];
    int t = threadIdx.x;
    int mine = (t < m) ? in[t] : 0;
    s[t] = mine;
    __syncthreads();
    for (int off = 1; off < 1024; off <<= 1) {
        int add = (t >= off) ? s[t - off] : 0;
        __syncthreads();
        s[t] += add;
        __syncthreads();
    }
    if (t < m) outx[t] = s[t] - mine;   // exclusive
}

__global__ void k_scan3(int* __restrict__ rowstart, const int* __restrict__ boff,
                        const int* __restrict__ deg, int* __restrict__ cursor,
                        float* __restrict__ dis, int n) {
    int i = blockIdx.x * blockDim.x + threadIdx.x;
    if (i >= n) return;
    int r = rowstart[i] + boff[i >> 10];
    rowstart[i] = r;
    cursor[i] = r;
    dis[i] = rsqrtf((float)(deg[i] + 1));   // +1 self-loop
}

// ---------------- phase 2: bucket-local CSR fill (L2-local cursors + writes) ----------------
__global__ __launch_bounds__(256) void k_fill2(const unsigned* __restrict__ bpk,
                                               const int* __restrict__ bstart, int B, int E,
                                               int* __restrict__ cursor,
                                               int* __restrict__ ssrc) {
    __shared__ int sb[MAXB + 1];
    int t = threadIdx.x;
    for (int i = t; i <= B; i += 256) sb[i] = bstart[i];
    __syncthreads();
    int i0 = blockIdx.x * 4096;
    int i1 = min(i0 + 4096, E);
    for (int i = i0 + t; i < i1; i += 256) {
        // binary search: b such that sb[b] <= i < sb[b+1]
        int lo = 0, hi = B;
        while (hi - lo > 1) { int mid = (lo + hi) >> 1; if (i >= sb[mid]) lo = mid; else hi = mid; }
        unsigned pk = bpk[i];
        int d = (lo << BSHIFT) + (int)(pk >> 18);
        int pos = atomicAdd(&cursor[d], 1);
        ssrc[pos] = (int)(pk & 0x3FFFFu);
    }
}

// ---------------- per-layer transform: g[i,c] = dis[i] * (h[i,:] @ W[:,c]) ----------------
template<int FIN, int FOUT>
__global__ void k_transform(const float* __restrict__ h, int ldh,
                            const float* __restrict__ W,
                            const float* __restrict__ dis,
                            float* __restrict__ g, int n) {
    int t = blockIdx.x * blockDim.x + threadIdx.x;
    int i = t / FOUT, c = t % FOUT;
    if (i >= n) return;
    const float* hr = h + (size_t)i * ldh;
    float a = 0.f;
#pragma unroll
    for (int f = 0; f < FIN; ++f) a += hr[f] * W[f * FOUT + c];
    g[(size_t)i * FOUT + c] = dis[i] * a;
}

// ---------------- CSR gather + finalize, FOUT=32: 8 lanes/node, float4 each ----------------
__global__ void k_gather32(const int* __restrict__ rowstart, const int* __restrict__ deg,
                           const int* __restrict__ ssrc, const float4* __restrict__ g4,
                           const float* __restrict__ dis, const float* __restrict__ b,
                           float* __restrict__ feat, int off, int n) {
    int t = blockIdx.x * blockDim.x + threadIdx.x;
    int i = t >> 3, p = t & 7;
    if (i >= n) return;
    int r0 = rowstart[i], d = deg[i];
    float4 acc = g4[(size_t)i * 8 + p];   // self-loop term
    for (int j = 0; j < d; ++j) {
        int s = ssrc[r0 + j];
        float4 v = g4[(size_t)s * 8 + p];
        acc.x += v.x; acc.y += v.y; acc.z += v.z; acc.w += v.w;
    }
    float sc = dis[i];
    float* fr = feat + (size_t)i * D_TOT + off + p * 4;
    fr[0] = tanhf(sc * acc.x + b[p * 4 + 0]);
    fr[1] = tanhf(sc * acc.y + b[p * 4 + 1]);
    fr[2] = tanhf(sc * acc.z + b[p * 4 + 2]);
    fr[3] = tanhf(sc * acc.w + b[p * 4 + 3]);
}

// ---------------- CSR gather + finalize, FOUT=1 ----------------
__global__ void k_gather1(const int* __restrict__ rowstart, const int* __restrict__ deg,
                          const int* __restrict__ ssrc, const float* __restrict__ g,
                          const float* __restrict__ dis, const float* __restrict__ b,
                          float* __restrict__ feat, int off, int n) {
    int i = blockIdx.x * blockDim.x + threadIdx.x;
    if (i >= n) return;
    int r0 = rowstart[i], d = deg[i];
    float acc = g[i];
    for (int j = 0; j < d; ++j) acc += g[ssrc[r0 + j]];
    feat[(size_t)i * D_TOT + off] = tanhf(dis[i] * acc + b[0]);
}

// ---------------- per-graph counts ----------------
__global__ void k_hist(const int* __restrict__ batch, int n, int* __restrict__ counts) {
    int i = blockIdx.x * blockDim.x + threadIdx.x;
    if (i < n) atomicAdd(&counts[batch[i]], 1);
}

// ---------------- fused sort-pool + conv1 + maxpool + conv2 + MLP, one block/graph ----------------
constexpr int MAXN_G = 1024;

__global__ __launch_bounds__(128) void k_cnn(
    const float* __restrict__ feat,
    const int* __restrict__ starts, const int* __restrict__ counts,
    const float* __restrict__ c1w, const float* __restrict__ c1b,
    const float* __restrict__ c2w, const float* __restrict__ c2b,
    const float* __restrict__ m1w, const float* __restrict__ m1b,
    const float* __restrict__ m2w, const float* __restrict__ m2b,
    float* __restrict__ out)
{
    int g = blockIdx.x;
    int tid = threadIdx.x;

    __shared__ float vals[MAXN_G];
    __shared__ int   sel[K_POOL];
    __shared__ float pooled[K_POOL][D_TOT];
    __shared__ float y[16][K_POOL];
    __shared__ float z[16][15];
    __shared__ float u[352];
    __shared__ float hid[32];
    __shared__ float red[128];
    __shared__ int   redi[128];

    int start = starts[g];
    int cnt = counts[g];
    if (cnt > MAXN_G) cnt = MAXN_G;
    int kk = cnt < K_POOL ? cnt : K_POOL;

    for (int i = tid; i < cnt; i += 128)
        vals[i] = feat[(size_t)(start + i) * D_TOT + (D_TOT - 1)];
    __syncthreads();

    for (int k = 0; k < kk; ++k) {
        float bv = NEG; int bi = 0x7fffffff;
        for (int i = tid; i < cnt; i += 128) {
            float v = vals[i];
            if (v > bv || (v == bv && i < bi)) { bv = v; bi = i; }
        }
        red[tid] = bv; redi[tid] = bi;
        __syncthreads();
        for (int s2 = 64; s2 > 0; s2 >>= 1) {
            if (tid < s2) {
                float ov = red[tid + s2]; int oi = redi[tid + s2];
                if (ov > red[tid] || (ov == red[tid] && oi < redi[tid])) {
                    red[tid] = ov; redi[tid] = oi;
                }
            }
            __syncthreads();
        }
        if (tid == 0) { sel[k] = redi[0]; vals[redi[0]] = NEG; }
        __syncthreads();
    }

    float* pf = &pooled[0][0];
    for (int t = tid; t < K_POOL * D_TOT; t += 128) pf[t] = 0.f;
    __syncthreads();
    for (int t = tid; t < kk * D_TOT; t += 128) {
        int r = t / D_TOT, c = t - r * D_TOT;
        pf[t] = feat[(size_t)(start + sel[r]) * D_TOT + c];
    }
    __syncthreads();

    for (int t = tid; t < 16 * K_POOL; t += 128) {
        int o = t / K_POOL, p = t - o * K_POOL;
        float a = c1b[o];
        const float* w = c1w + o * D_TOT;
        const float* pr = &pooled[p][0];
#pragma unroll 1
        for (int c = 0; c < D_TOT; ++c) a += pr[c] * w[c];
        y[o][p] = fmaxf(a, 0.f);
    }
    __syncthreads();

    for (int t = tid; t < 16 * 15; t += 128) {
        int o = t / 15, p = t - o * 15;
        z[o][p] = fmaxf(y[o][2 * p], y[o][2 * p + 1]);
    }
    __syncthreads();

    for (int t = tid; t < 32 * 11; t += 128) {
        int q = t / 11, p = t - q * 11;
        float a = c2b[q];
        const float* w = c2w + q * 16 * 5;
#pragma unroll 1
        for (int c = 0; c < 16; ++c) {
#pragma unroll
            for (int j = 0; j < 5; ++j) a += z[c][p + j] * w[c * 5 + j];
        }
        u[t] = fmaxf(a, 0.f);
    }
    __syncthreads();

    if (tid < 32) {
        float a = m1b[tid];
        for (int i = 0; i < 352; ++i) a += u[i] * m1w[i * 32 + tid];
        hid[tid] = fmaxf(a, 0.f);
    }
    __syncthreads();

    if (tid == 0) {
        float a = m2b[0];
#pragma unroll
        for (int m = 0; m < 32; ++m) a += hid[m] * m2w[m];
        out[g] = a;
    }
}

// ---------------- launch ----------------
extern "C" void kernel_launch(void* const* d_in, const int* in_sizes, int n_in,
                              void* d_out, int out_size, void* d_ws, size_t ws_size,
                              hipStream_t stream) {
    const float* x    = (const float*)d_in[0];
    const int*   ei   = (const int*)d_in[1];
    const int*   batch= (const int*)d_in[2];
    const float* W0   = (const float*)d_in[3];
    const float* b0   = (const float*)d_in[4];
    const float* W1   = (const float*)d_in[5];
    const float* b1   = (const float*)d_in[6];
    const float* W2   = (const float*)d_in[7];
    const float* b2   = (const float*)d_in[8];
    const float* W3   = (const float*)d_in[9];
    const float* b3   = (const float*)d_in[10];
    const float* c1w  = (const float*)d_in[11];
    const float* c1b  = (const float*)d_in[12];
    const float* c2w  = (const float*)d_in[13];
    const float* c2b  = (const float*)d_in[14];
    const float* m1w  = (const float*)d_in[15];
    const float* m1b  = (const float*)d_in[16];
    const float* m2w  = (const float*)d_in[17];
    const float* m2b  = (const float*)d_in[18];

    const int n = in_sizes[0] / 20;
    const int E = in_sizes[1] / 2;
    const int G = out_size;
    const int* srcv = ei;
    const int* dstv = ei + E;
    const int nb = (n + 1023) / 1024;
    const int B = (n + (1 << BSHIFT) - 1) >> BSHIFT;   // buckets
    const int nE4 = (E + 4095) / 4096;

    char* ws = (char*)d_ws;
    float* feat    = (float*)ws;  ws += (size_t)n * D_TOT * sizeof(float);
    float* gbuf    = (float*)ws;  ws += (size_t)n * 32 * sizeof(float);
    int*   ssrc    = (int*)ws;    ws += (size_t)E * sizeof(int);
    unsigned* bpk  = (unsigned*)ws; ws += (size_t)E * sizeof(unsigned);
    int*   rowstart= (int*)ws;    ws += (size_t)n * sizeof(int);
    int*   cursor  = (int*)ws;    ws += (size_t)n * sizeof(int);
    int*   deg     = (int*)ws;    ws += (size_t)n * sizeof(int);
    float* dis     = (float*)ws;  ws += (size_t)n * sizeof(float);
    int*   bsum    = (int*)ws;    ws += (size_t)nb * sizeof(int);
    int*   boff    = (int*)ws;    ws += (size_t)nb * sizeof(int);
    int*   counts  = (int*)ws;    ws += (size_t)G * sizeof(int);
    int*   startsb = (int*)ws;    ws += (size_t)G * sizeof(int);
    int*   bucketcnt=(int*)ws;    ws += (size_t)(MAXB) * sizeof(int);
    int*   bstart  = (int*)ws;    ws += (size_t)(MAXB + 1) * sizeof(int);
    int*   bcursor = (int*)ws;    ws += (size_t)(MAXB) * sizeof(int);

    hipMemsetAsync(deg, 0, (size_t)n * sizeof(int), stream);
    hipMemsetAsync(counts, 0, (size_t)G * sizeof(int), stream);
    hipMemsetAsync(bucketcnt, 0, (size_t)MAXB * sizeof(int), stream);

    // CSR build (bucketed; reused by all 4 layers)
    k_bcount<<<nE4, 256, 0, stream>>>(dstv, E, deg, bucketcnt, B);
    k_bscan<<<1, MAXB, 0, stream>>>(bucketcnt, bstart, bcursor, B, E);
    k_part<<<nE4, 256, 0, stream>>>(srcv, dstv, E, B, bcursor, bpk);
    k_scan1<<<nb, 1024, 0, stream>>>(deg, n, rowstart, bsum);
    k_scan2<<<1, 1024, 0, stream>>>(bsum, boff, nb);
    k_scan3<<<(n + 255) / 256, 256, 0, stream>>>(rowstart, boff, deg, cursor, dis, n);
    k_fill2<<<nE4, 256, 0, stream>>>(bpk, bstart, B, E, cursor, ssrc);

    // per-graph segments
    k_hist<<<(n + 255) / 256, 256, 0, stream>>>(batch, n, counts);
    k_scan2<<<1, 1024, 0, stream>>>(counts, startsb, G);

    const int nt32 = n * 32;
    const int nt8  = n * 8;
    // layer 0: 20 -> 32
    k_transform<20, 32><<<(nt32 + 255) / 256, 256, 0, stream>>>(x, 20, W0, dis, gbuf, n);
    k_gather32<<<(nt8 + 255) / 256, 256, 0, stream>>>(rowstart, deg, ssrc, (const float4*)gbuf, dis, b0, feat, 0, n);
    // layer 1
    k_transform<32, 32><<<(nt32 + 255) / 256, 256, 0, stream>>>(feat + 0, D_TOT, W1, dis, gbuf, n);
    k_gather32<<<(nt8 + 255) / 256, 256, 0, stream>>>(rowstart, deg, ssrc, (const float4*)gbuf, dis, b1, feat, 32, n);
    // layer 2
    k_transform<32, 32><<<(nt32 + 255) / 256, 256, 0, stream>>>(feat + 32, D_TOT, W2, dis, gbuf, n);
    k_gather32<<<(nt8 + 255) / 256, 256, 0, stream>>>(rowstart, deg, ssrc, (const float4*)gbuf, dis, b2, feat, 64, n);
    // layer 3: 32 -> 1
    k_transform<32, 1><<<(n + 255) / 256, 256, 0, stream>>>(feat + 64, D_TOT, W3, dis, gbuf, n);
    k_gather1<<<(n + 255) / 256, 256, 0, stream>>>(rowstart, deg, ssrc, gbuf, dis, b3, feat, 96, n);

    // fused sort-pool + CNN + MLP
    k_cnn<<<G, 128, 0, stream>>>(feat, startsb, counts,
                                 c1w, c1b, c2w, c2b, m1w, m1b, m2w, m2b,
                                 (float*)d_out);
}

// Round 4
// 647.178 us; speedup vs baseline: 1.3484x; 1.3484x over previous
//
#include <hip/hip_runtime.h>
#include <math.h>

constexpr int D_TOT = 97;
constexpr int K_POOL = 30;
constexpr float NEG = -3.0e38f;
constexpr int BSHIFT = 10;                 // 1024 nodes per bucket
constexpr int BSIZE  = 1 << BSHIFT;
constexpr int MAXB   = 256;                // max buckets (n < 262144)

// ---------------- bucket histogram (LDS-aggregated) ----------------
__global__ __launch_bounds__(256) void k_bcount(const int* __restrict__ dst, int E,
                                                int* __restrict__ bucketcnt, int B) {
    __shared__ int h[MAXB];
    int t = threadIdx.x;
    for (int i = t; i < MAXB; i += 256) h[i] = 0;
    __syncthreads();
    int e0 = blockIdx.x * 4096;
    int e1 = min(e0 + 4096, E);
    for (int i = e0 + t; i < e1; i += 256)
        atomicAdd(&h[dst[i] >> BSHIFT], 1);
    __syncthreads();
    for (int i = t; i < B; i += 256)
        if (h[i]) atomicAdd(&bucketcnt[i], h[i]);
}

// ---------------- bucket exclusive scan ----------------
__global__ void k_bscan(const int* __restrict__ cnt, int* __restrict__ bstart,
                        int* __restrict__ bcursor, int B, int E) {
    __shared__ int s[MAXB];
    int t = threadIdx.x;          // blockDim = 256
    int mine = (t < B) ? cnt[t] : 0;
    s[t] = mine;
    __syncthreads();
    for (int off = 1; off < MAXB; off <<= 1) {
        int add = (t >= off) ? s[t - off] : 0;
        __syncthreads();
        s[t] += add;
        __syncthreads();
    }
    if (t < B) { int ex = s[t] - mine; bstart[t] = ex; bcursor[t] = ex; }
    if (t == 0) bstart[B] = E;
}

// ---------------- phase 1: partition edges into bucket-contiguous packed array ----------------
__global__ __launch_bounds__(256) void k_part(const int* __restrict__ src,
                                              const int* __restrict__ dst, int E, int B,
                                              int* __restrict__ bcursor,
                                              unsigned* __restrict__ bpk) {
    __shared__ int s_src[8192];
    __shared__ int s_dst[8192];
    __shared__ int hist[MAXB];
    __shared__ int base[MAXB];
    int t = threadIdx.x;
    int e0 = blockIdx.x * 8192;
    int cnt = min(8192, E - e0);
    for (int i = t; i < MAXB; i += 256) hist[i] = 0;
    __syncthreads();
    for (int i = t; i < cnt; i += 256) {
        int d = dst[e0 + i];
        s_src[i] = src[e0 + i];
        s_dst[i] = d;
        atomicAdd(&hist[d >> BSHIFT], 1);
    }
    __syncthreads();
    for (int i = t; i < B; i += 256) {
        int hh = hist[i];
        base[i] = hh ? atomicAdd(&bcursor[i], hh) : 0;
        hist[i] = 0;
    }
    __syncthreads();
    for (int i = t; i < cnt; i += 256) {
        int d = s_dst[i];
        int b = d >> BSHIFT;
        int off = atomicAdd(&hist[b], 1);
        bpk[base[b] + off] = ((unsigned)(d & (BSIZE - 1)) << 18) | (unsigned)s_src[i];
    }
}

// ---------------- phase 2: one block per bucket — LDS count+scan+scatter, no global atomics ----------------
__global__ __launch_bounds__(256) void k_fill3(const unsigned* __restrict__ bpk,
                                               const int* __restrict__ bstart,
                                               int n, int B,
                                               int* __restrict__ deg,
                                               int* __restrict__ rowstart,
                                               float* __restrict__ dis,
                                               int* __restrict__ ssrc) {
    __shared__ int cnt[BSIZE];     // per-node count -> absolute cursor
    __shared__ int s256[256];
    int b = blockIdx.x;
    int t = threadIdx.x;
    int s0 = bstart[b], s1 = bstart[b + 1];

    for (int i = t; i < BSIZE; i += 256) cnt[i] = 0;
    __syncthreads();
    // pass 1: count local degrees
    for (int i = s0 + t; i < s1; i += 256)
        atomicAdd(&cnt[bpk[i] >> 18], 1);
    __syncthreads();

    // block scan of 1024 counts (4 per thread)
    int c0 = cnt[4 * t], c1 = cnt[4 * t + 1], c2 = cnt[4 * t + 2], c3 = cnt[4 * t + 3];
    int tot = c0 + c1 + c2 + c3;
    s256[t] = tot;
    __syncthreads();
    for (int off = 1; off < 256; off <<= 1) {
        int add = (t >= off) ? s256[t - off] : 0;
        __syncthreads();
        s256[t] += add;
        __syncthreads();
    }
    int g0 = s0 + s256[t] - tot;   // absolute exclusive position of node 4t
    int p0 = g0, p1 = g0 + c0, p2 = p1 + c1, p3 = p2 + c2;

    // emit rowstart/deg/dis for the 4 nodes
    int node0 = (b << BSHIFT) + 4 * t;
    if (node0 + 0 < n) { rowstart[node0 + 0] = p0; deg[node0 + 0] = c0; dis[node0 + 0] = rsqrtf((float)(c0 + 1)); }
    if (node0 + 1 < n) { rowstart[node0 + 1] = p1; deg[node0 + 1] = c1; dis[node0 + 1] = rsqrtf((float)(c1 + 1)); }
    if (node0 + 2 < n) { rowstart[node0 + 2] = p2; deg[node0 + 2] = c2; dis[node0 + 2] = rsqrtf((float)(c2 + 1)); }
    if (node0 + 3 < n) { rowstart[node0 + 3] = p3; deg[node0 + 3] = c3; dis[node0 + 3] = rsqrtf((float)(c3 + 1)); }

    // counts -> absolute cursors
    cnt[4 * t] = p0; cnt[4 * t + 1] = p1; cnt[4 * t + 2] = p2; cnt[4 * t + 3] = p3;
    __syncthreads();

    // pass 2: scatter via LDS cursors (writes stay in this bucket's contiguous window)
    for (int i = s0 + t; i < s1; i += 256) {
        unsigned pk = bpk[i];
        int pos = atomicAdd(&cnt[pk >> 18], 1);
        ssrc[pos] = (int)(pk & 0x3FFFFu);
    }
}

// ---------------- per-layer transform: g[i,c] = dis[i] * (h[i,:] @ W[:,c]) ----------------
template<int FIN, int FOUT>
__global__ void k_transform(const float* __restrict__ h, int ldh,
                            const float* __restrict__ W,
                            const float* __restrict__ dis,
                            float* __restrict__ g, int n) {
    int t = blockIdx.x * blockDim.x + threadIdx.x;
    int i = t / FOUT, c = t % FOUT;
    if (i >= n) return;
    const float* hr = h + (size_t)i * ldh;
    float a = 0.f;
#pragma unroll
    for (int f = 0; f < FIN; ++f) a += hr[f] * W[f * FOUT + c];
    g[(size_t)i * FOUT + c] = dis[i] * a;
}

// ---------------- CSR gather + finalize, FOUT=32: 8 lanes/node, float4 each ----------------
__global__ void k_gather32(const int* __restrict__ rowstart, const int* __restrict__ deg,
                           const int* __restrict__ ssrc, const float4* __restrict__ g4,
                           const float* __restrict__ dis, const float* __restrict__ b,
                           float* __restrict__ feat, int off, int n) {
    int t = blockIdx.x * blockDim.x + threadIdx.x;
    int i = t >> 3, p = t & 7;
    if (i >= n) return;
    int r0 = rowstart[i], d = deg[i];
    float4 acc = g4[(size_t)i * 8 + p];   // self-loop term
    for (int j = 0; j < d; ++j) {
        int s = ssrc[r0 + j];
        float4 v = g4[(size_t)s * 8 + p];
        acc.x += v.x; acc.y += v.y; acc.z += v.z; acc.w += v.w;
    }
    float sc = dis[i];
    float* fr = feat + (size_t)i * D_TOT + off + p * 4;
    fr[0] = tanhf(sc * acc.x + b[p * 4 + 0]);
    fr[1] = tanhf(sc * acc.y + b[p * 4 + 1]);
    fr[2] = tanhf(sc * acc.z + b[p * 4 + 2]);
    fr[3] = tanhf(sc * acc.w + b[p * 4 + 3]);
}

// ---------------- CSR gather + finalize, FOUT=1 ----------------
__global__ void k_gather1(const int* __restrict__ rowstart, const int* __restrict__ deg,
                          const int* __restrict__ ssrc, const float* __restrict__ g,
                          const float* __restrict__ dis, const float* __restrict__ b,
                          float* __restrict__ feat, int off, int n) {
    int i = blockIdx.x * blockDim.x + threadIdx.x;
    if (i >= n) return;
    int r0 = rowstart[i], d = deg[i];
    float acc = g[i];
    for (int j = 0; j < d; ++j) acc += g[ssrc[r0 + j]];
    feat[(size_t)i * D_TOT + off] = tanhf(dis[i] * acc + b[0]);
}

// ---------------- per-graph counts ----------------
__global__ void k_hist(const int* __restrict__ batch, int n, int* __restrict__ counts) {
    int i = blockIdx.x * blockDim.x + threadIdx.x;
    if (i < n) atomicAdd(&counts[batch[i]], 1);
}

__global__ void k_scan2(const int* __restrict__ in, int* __restrict__ outx, int m) {
    __shared__ int s[1024];
    int t = threadIdx.x;
    int mine = (t < m) ? in[t] : 0;
    s[t] = mine;
    __syncthreads();
    for (int off = 1; off < 1024; off <<= 1) {
        int add = (t >= off) ? s[t - off] : 0;
        __syncthreads();
        s[t] += add;
        __syncthreads();
    }
    if (t < m) outx[t] = s[t] - mine;   // exclusive
}

// ---------------- fused sort-pool + conv1 + maxpool + conv2 + MLP, one block/graph ----------------
constexpr int MAXN_G = 1024;

__global__ __launch_bounds__(128) void k_cnn(
    const float* __restrict__ feat,
    const int* __restrict__ starts, const int* __restrict__ counts,
    const float* __restrict__ c1w, const float* __restrict__ c1b,
    const float* __restrict__ c2w, const float* __restrict__ c2b,
    const float* __restrict__ m1w, const float* __restrict__ m1b,
    const float* __restrict__ m2w, const float* __restrict__ m2b,
    float* __restrict__ out)
{
    int g = blockIdx.x;
    int tid = threadIdx.x;

    __shared__ float vals[MAXN_G];
    __shared__ int   sel[K_POOL];
    __shared__ float pooled[K_POOL][D_TOT];
    __shared__ float y[16][K_POOL];
    __shared__ float z[16][15];
    __shared__ float u[352];
    __shared__ float hid[32];
    __shared__ float red[128];
    __shared__ int   redi[128];

    int start = starts[g];
    int cnt = counts[g];
    if (cnt > MAXN_G) cnt = MAXN_G;
    int kk = cnt < K_POOL ? cnt : K_POOL;

    for (int i = tid; i < cnt; i += 128)
        vals[i] = feat[(size_t)(start + i) * D_TOT + (D_TOT - 1)];
    __syncthreads();

    for (int k = 0; k < kk; ++k) {
        float bv = NEG; int bi = 0x7fffffff;
        for (int i = tid; i < cnt; i += 128) {
            float v = vals[i];
            if (v > bv || (v == bv && i < bi)) { bv = v; bi = i; }
        }
        red[tid] = bv; redi[tid] = bi;
        __syncthreads();
        for (int s2 = 64; s2 > 0; s2 >>= 1) {
            if (tid < s2) {
                float ov = red[tid + s2]; int oi = redi[tid + s2];
                if (ov > red[tid] || (ov == red[tid] && oi < redi[tid])) {
                    red[tid] = ov; redi[tid] = oi;
                }
            }
            __syncthreads();
        }
        if (tid == 0) { sel[k] = redi[0]; vals[redi[0]] = NEG; }
        __syncthreads();
    }

    float* pf = &pooled[0][0];
    for (int t = tid; t < K_POOL * D_TOT; t += 128) pf[t] = 0.f;
    __syncthreads();
    for (int t = tid; t < kk * D_TOT; t += 128) {
        int r = t / D_TOT, c = t - r * D_TOT;
        pf[t] = feat[(size_t)(start + sel[r]) * D_TOT + c];
    }
    __syncthreads();

    for (int t = tid; t < 16 * K_POOL; t += 128) {
        int o = t / K_POOL, p = t - o * K_POOL;
        float a = c1b[o];
        const float* w = c1w + o * D_TOT;
        const float* pr = &pooled[p][0];
#pragma unroll 1
        for (int c = 0; c < D_TOT; ++c) a += pr[c] * w[c];
        y[o][p] = fmaxf(a, 0.f);
    }
    __syncthreads();

    for (int t = tid; t < 16 * 15; t += 128) {
        int o = t / 15, p = t - o * 15;
        z[o][p] = fmaxf(y[o][2 * p], y[o][2 * p + 1]);
    }
    __syncthreads();

    for (int t = tid; t < 32 * 11; t += 128) {
        int q = t / 11, p = t - q * 11;
        float a = c2b[q];
        const float* w = c2w + q * 16 * 5;
#pragma unroll 1
        for (int c = 0; c < 16; ++c) {
#pragma unroll
            for (int j = 0; j < 5; ++j) a += z[c][p + j] * w[c * 5 + j];
        }
        u[t] = fmaxf(a, 0.f);
    }
    __syncthreads();

    if (tid < 32) {
        float a = m1b[tid];
        for (int i = 0; i < 352; ++i) a += u[i] * m1w[i * 32 + tid];
        hid[tid] = fmaxf(a, 0.f);
    }
    __syncthreads();

    if (tid == 0) {
        float a = m2b[0];
#pragma unroll
        for (int m = 0; m < 32; ++m) a += hid[m] * m2w[m];
        out[g] = a;
    }
}

// ---------------- launch ----------------
extern "C" void kernel_launch(void* const* d_in, const int* in_sizes, int n_in,
                              void* d_out, int out_size, void* d_ws, size_t ws_size,
                              hipStream_t stream) {
    const float* x    = (const float*)d_in[0];
    const int*   ei   = (const int*)d_in[1];
    const int*   batch= (const int*)d_in[2];
    const float* W0   = (const float*)d_in[3];
    const float* b0   = (const float*)d_in[4];
    const float* W1   = (const float*)d_in[5];
    const float* b1   = (const float*)d_in[6];
    const float* W2   = (const float*)d_in[7];
    const float* b2   = (const float*)d_in[8];
    const float* W3   = (const float*)d_in[9];
    const float* b3   = (const float*)d_in[10];
    const float* c1w  = (const float*)d_in[11];
    const float* c1b  = (const float*)d_in[12];
    const float* c2w  = (const float*)d_in[13];
    const float* c2b  = (const float*)d_in[14];
    const float* m1w  = (const float*)d_in[15];
    const float* m1b  = (const float*)d_in[16];
    const float* m2w  = (const float*)d_in[17];
    const float* m2b  = (const float*)d_in[18];

    const int n = in_sizes[0] / 20;
    const int E = in_sizes[1] / 2;
    const int G = out_size;
    const int* srcv = ei;
    const int* dstv = ei + E;
    const int B = (n + BSIZE - 1) >> BSHIFT;           // buckets
    const int nE4 = (E + 4095) / 4096;
    const int nE8 = (E + 8191) / 8192;

    char* ws = (char*)d_ws;
    float* feat    = (float*)ws;  ws += (size_t)n * D_TOT * sizeof(float);
    float* gbuf    = (float*)ws;  ws += (size_t)n * 32 * sizeof(float);
    int*   ssrc    = (int*)ws;    ws += (size_t)E * sizeof(int);
    unsigned* bpk  = (unsigned*)ws; ws += (size_t)E * sizeof(unsigned);
    int*   rowstart= (int*)ws;    ws += (size_t)n * sizeof(int);
    int*   deg     = (int*)ws;    ws += (size_t)n * sizeof(int);
    float* dis     = (float*)ws;  ws += (size_t)n * sizeof(float);
    int*   counts  = (int*)ws;    ws += (size_t)G * sizeof(int);
    int*   startsb = (int*)ws;    ws += (size_t)G * sizeof(int);
    int*   bucketcnt=(int*)ws;    ws += (size_t)MAXB * sizeof(int);
    int*   bstart  = (int*)ws;    ws += (size_t)(MAXB + 1) * sizeof(int);
    int*   bcursor = (int*)ws;    ws += (size_t)MAXB * sizeof(int);

    hipMemsetAsync(counts, 0, (size_t)G * sizeof(int), stream);
    hipMemsetAsync(bucketcnt, 0, (size_t)MAXB * sizeof(int), stream);

    // CSR build (bucketed, no global data atomics; reused by all 4 layers)
    k_bcount<<<nE4, 256, 0, stream>>>(dstv, E, bucketcnt, B);
    k_bscan<<<1, MAXB, 0, stream>>>(bucketcnt, bstart, bcursor, B, E);
    k_part<<<nE8, 256, 0, stream>>>(srcv, dstv, E, B, bcursor, bpk);
    k_fill3<<<B, 256, 0, stream>>>(bpk, bstart, n, B, deg, rowstart, dis, ssrc);

    // per-graph segments
    k_hist<<<(n + 255) / 256, 256, 0, stream>>>(batch, n, counts);
    k_scan2<<<1, 1024, 0, stream>>>(counts, startsb, G);

    const int nt32 = n * 32;
    const int nt8  = n * 8;
    // layer 0: 20 -> 32
    k_transform<20, 32><<<(nt32 + 255) / 256, 256, 0, stream>>>(x, 20, W0, dis, gbuf, n);
    k_gather32<<<(nt8 + 255) / 256, 256, 0, stream>>>(rowstart, deg, ssrc, (const float4*)gbuf, dis, b0, feat, 0, n);
    // layer 1
    k_transform<32, 32><<<(nt32 + 255) / 256, 256, 0, stream>>>(feat + 0, D_TOT, W1, dis, gbuf, n);
    k_gather32<<<(nt8 + 255) / 256, 256, 0, stream>>>(rowstart, deg, ssrc, (const float4*)gbuf, dis, b1, feat, 32, n);
    // layer 2
    k_transform<32, 32><<<(nt32 + 255) / 256, 256, 0, stream>>>(feat + 32, D_TOT, W2, dis, gbuf, n);
    k_gather32<<<(nt8 + 255) / 256, 256, 0, stream>>>(rowstart, deg, ssrc, (const float4*)gbuf, dis, b2, feat, 64, n);
    // layer 3: 32 -> 1
    k_transform<32, 1><<<(n + 255) / 256, 256, 0, stream>>>(feat + 64, D_TOT, W3, dis, gbuf, n);
    k_gather1<<<(n + 255) / 256, 256, 0, stream>>>(rowstart, deg, ssrc, gbuf, dis, b3, feat, 96, n);

    // fused sort-pool + CNN + MLP
    k_cnn<<<G, 128, 0, stream>>>(feat, startsb, counts,
                                 c1w, c1b, c2w, c2b, m1w, m1b, m2w, m2b,
                                 (float*)d_out);
}

// Round 6
// 616.261 us; speedup vs baseline: 1.4160x; 1.0502x over previous
//
#include <hip/hip_runtime.h>
#include <math.h>

constexpr int D_TOT = 97;
constexpr int K_POOL = 30;
constexpr int BSHIFT = 10;                 // 1024 nodes per bucket
constexpr int BSIZE  = 1 << BSHIFT;
constexpr int MAXB   = 256;                // max buckets (n < 262144)

// ---------------- bucket histogram (LDS-aggregated) ----------------
__global__ __launch_bounds__(256) void k_bcount(const int* __restrict__ dst, int E,
                                                int* __restrict__ bucketcnt, int B) {
    __shared__ int h[MAXB];
    int t = threadIdx.x;
    for (int i = t; i < MAXB; i += 256) h[i] = 0;
    __syncthreads();
    int e0 = blockIdx.x * 4096;
    int e1 = min(e0 + 4096, E);
    for (int i = e0 + t; i < e1; i += 256)
        atomicAdd(&h[dst[i] >> BSHIFT], 1);
    __syncthreads();
    for (int i = t; i < B; i += 256)
        if (h[i]) atomicAdd(&bucketcnt[i], h[i]);
}

// ---------------- bucket exclusive scan ----------------
__global__ void k_bscan(const int* __restrict__ cnt, int* __restrict__ bstart,
                        int* __restrict__ bcursor, int B, int E) {
    __shared__ int s[MAXB];
    int t = threadIdx.x;          // blockDim = 256
    int mine = (t < B) ? cnt[t] : 0;
    s[t] = mine;
    __syncthreads();
    for (int off = 1; off < MAXB; off <<= 1) {
        int add = (t >= off) ? s[t - off] : 0;
        __syncthreads();
        s[t] += add;
        __syncthreads();
    }
    if (t < B) { int ex = s[t] - mine; bstart[t] = ex; bcursor[t] = ex; }
    if (t == 0) bstart[B] = E;
}

// ---------------- phase 1: partition edges into bucket-contiguous packed array ----------------
__global__ __launch_bounds__(256) void k_part(const int* __restrict__ src,
                                              const int* __restrict__ dst, int E, int B,
                                              int* __restrict__ bcursor,
                                              unsigned* __restrict__ bpk) {
    __shared__ int s_src[8192];
    __shared__ int s_dst[8192];
    __shared__ int hist[MAXB];
    __shared__ int base[MAXB];
    int t = threadIdx.x;
    int e0 = blockIdx.x * 8192;
    int cnt = min(8192, E - e0);
    for (int i = t; i < MAXB; i += 256) hist[i] = 0;
    __syncthreads();
    for (int i = t; i < cnt; i += 256) {
        int d = dst[e0 + i];
        s_src[i] = src[e0 + i];
        s_dst[i] = d;
        atomicAdd(&hist[d >> BSHIFT], 1);
    }
    __syncthreads();
    for (int i = t; i < B; i += 256) {
        int hh = hist[i];
        base[i] = hh ? atomicAdd(&bcursor[i], hh) : 0;
        hist[i] = 0;
    }
    __syncthreads();
    for (int i = t; i < cnt; i += 256) {
        int d = s_dst[i];
        int b = d >> BSHIFT;
        int off = atomicAdd(&hist[b], 1);
        bpk[base[b] + off] = ((unsigned)(d & (BSIZE - 1)) << 18) | (unsigned)s_src[i];
    }
}

// ---------------- phase 2: one block per bucket — LDS count+scan+scatter, no global atomics ----------------
__global__ __launch_bounds__(256) void k_fill3(const unsigned* __restrict__ bpk,
                                               const int* __restrict__ bstart,
                                               int n, int B,
                                               int* __restrict__ deg,
                                               int* __restrict__ rowstart,
                                               float* __restrict__ dis,
                                               int* __restrict__ ssrc) {
    __shared__ int cnt[BSIZE];     // per-node count -> absolute cursor
    __shared__ int s256[256];
    int b = blockIdx.x;
    int t = threadIdx.x;
    int s0 = bstart[b], s1 = bstart[b + 1];

    for (int i = t; i < BSIZE; i += 256) cnt[i] = 0;
    __syncthreads();
    for (int i = s0 + t; i < s1; i += 256)
        atomicAdd(&cnt[bpk[i] >> 18], 1);
    __syncthreads();

    int c0 = cnt[4 * t], c1 = cnt[4 * t + 1], c2 = cnt[4 * t + 2], c3 = cnt[4 * t + 3];
    int tot = c0 + c1 + c2 + c3;
    s256[t] = tot;
    __syncthreads();
    for (int off = 1; off < 256; off <<= 1) {
        int add = (t >= off) ? s256[t - off] : 0;
        __syncthreads();
        s256[t] += add;
        __syncthreads();
    }
    int g0 = s0 + s256[t] - tot;
    int p0 = g0, p1 = g0 + c0, p2 = p1 + c1, p3 = p2 + c2;

    int node0 = (b << BSHIFT) + 4 * t;
    if (node0 + 0 < n) { rowstart[node0 + 0] = p0; deg[node0 + 0] = c0; dis[node0 + 0] = rsqrtf((float)(c0 + 1)); }
    if (node0 + 1 < n) { rowstart[node0 + 1] = p1; deg[node0 + 1] = c1; dis[node0 + 1] = rsqrtf((float)(c1 + 1)); }
    if (node0 + 2 < n) { rowstart[node0 + 2] = p2; deg[node0 + 2] = c2; dis[node0 + 2] = rsqrtf((float)(c2 + 1)); }
    if (node0 + 3 < n) { rowstart[node0 + 3] = p3; deg[node0 + 3] = c3; dis[node0 + 3] = rsqrtf((float)(c3 + 1)); }

    cnt[4 * t] = p0; cnt[4 * t + 1] = p1; cnt[4 * t + 2] = p2; cnt[4 * t + 3] = p3;
    __syncthreads();

    for (int i = s0 + t; i < s1; i += 256) {
        unsigned pk = bpk[i];
        int pos = atomicAdd(&cnt[pk >> 18], 1);
        ssrc[pos] = (int)(pk & 0x3FFFFu);
    }
}

// ---------------- per-layer transform: g[i,c] = dis[i] * (h[i,:] @ W[:,c]) ----------------
template<int FIN, int FOUT>
__global__ void k_transform(const float* __restrict__ h, int ldh,
                            const float* __restrict__ W,
                            const float* __restrict__ dis,
                            float* __restrict__ g, int n) {
    int t = blockIdx.x * blockDim.x + threadIdx.x;
    int i = t / FOUT, c = t % FOUT;
    if (i >= n) return;
    const float* hr = h + (size_t)i * ldh;
    float a = 0.f;
#pragma unroll
    for (int f = 0; f < FIN; ++f) a += hr[f] * W[f * FOUT + c];
    g[(size_t)i * FOUT + c] = dis[i] * a;
}

// ---------------- CSR gather + finalize, FOUT=32: 8 lanes/node, float4 each; unroll-4 ----------------
__global__ void k_gather32(const int* __restrict__ rowstart, const int* __restrict__ deg,
                           const int* __restrict__ ssrc, const float4* __restrict__ g4,
                           const float* __restrict__ dis, const float* __restrict__ b,
                           float* __restrict__ feat, int off, int n) {
    int t = blockIdx.x * blockDim.x + threadIdx.x;
    int i = t >> 3, p = t & 7;
    if (i >= n) return;
    int r0 = rowstart[i], d = deg[i];
    float4 acc = g4[(size_t)i * 8 + p];   // self-loop term
    int j = 0;
    for (; j + 4 <= d; j += 4) {
        int s0 = ssrc[r0 + j + 0];
        int s1 = ssrc[r0 + j + 1];
        int s2 = ssrc[r0 + j + 2];
        int s3 = ssrc[r0 + j + 3];
        float4 v0 = g4[(size_t)s0 * 8 + p];
        float4 v1 = g4[(size_t)s1 * 8 + p];
        float4 v2 = g4[(size_t)s2 * 8 + p];
        float4 v3 = g4[(size_t)s3 * 8 + p];
        acc.x += (v0.x + v1.x) + (v2.x + v3.x);
        acc.y += (v0.y + v1.y) + (v2.y + v3.y);
        acc.z += (v0.z + v1.z) + (v2.z + v3.z);
        acc.w += (v0.w + v1.w) + (v2.w + v3.w);
    }
    for (; j < d; ++j) {
        int s = ssrc[r0 + j];
        float4 v = g4[(size_t)s * 8 + p];
        acc.x += v.x; acc.y += v.y; acc.z += v.z; acc.w += v.w;
    }
    float sc = dis[i];
    float* fr = feat + (size_t)i * D_TOT + off + p * 4;
    fr[0] = tanhf(sc * acc.x + b[p * 4 + 0]);
    fr[1] = tanhf(sc * acc.y + b[p * 4 + 1]);
    fr[2] = tanhf(sc * acc.z + b[p * 4 + 2]);
    fr[3] = tanhf(sc * acc.w + b[p * 4 + 3]);
}

// ---------------- CSR gather + finalize, FOUT=1 (f32, table is L2-resident) ----------------
__global__ void k_gather1(const int* __restrict__ rowstart, const int* __restrict__ deg,
                          const int* __restrict__ ssrc, const float* __restrict__ g,
                          const float* __restrict__ dis, const float* __restrict__ b,
                          float* __restrict__ feat, int off, int n) {
    int i = blockIdx.x * blockDim.x + threadIdx.x;
    if (i >= n) return;
    int r0 = rowstart[i], d = deg[i];
    float acc = g[i];
    for (int j = 0; j < d; ++j) acc += g[ssrc[r0 + j]];
    feat[(size_t)i * D_TOT + off] = tanhf(dis[i] * acc + b[0]);
}

// ---------------- per-graph counts ----------------
__global__ void k_hist(const int* __restrict__ batch, int n, int* __restrict__ counts) {
    int i = blockIdx.x * blockDim.x + threadIdx.x;
    if (i < n) atomicAdd(&counts[batch[i]], 1);
}

__global__ void k_scan2(const int* __restrict__ in, int* __restrict__ outx, int m) {
    __shared__ int s[1024];
    int t = threadIdx.x;
    int mine = (t < m) ? in[t] : 0;
    s[t] = mine;
    __syncthreads();
    for (int off = 1; off < 1024; off <<= 1) {
        int add = (t >= off) ? s[t - off] : 0;
        __syncthreads();
        s[t] += add;
        __syncthreads();
    }
    if (t < m) outx[t] = s[t] - mine;   // exclusive
}

// ---------------- fused sort-pool (bitonic) + conv1 + maxpool + conv2 + MLP ----------------
constexpr int SORTN = 512;

__global__ __launch_bounds__(256) void k_cnn(
    const float* __restrict__ feat,
    const int* __restrict__ starts, const int* __restrict__ counts,
    const float* __restrict__ c1w, const float* __restrict__ c1b,
    const float* __restrict__ c2w, const float* __restrict__ c2b,
    const float* __restrict__ m1w, const float* __restrict__ m1b,
    const float* __restrict__ m2w, const float* __restrict__ m2b,
    float* __restrict__ out)
{
    int g = blockIdx.x;
    int tid = threadIdx.x;   // 256

    __shared__ unsigned long long keys[SORTN];
    __shared__ float pooled[K_POOL][D_TOT];
    __shared__ float y[16][K_POOL];
    __shared__ float z[16][15];
    __shared__ float u[352];
    __shared__ float pm[256];
    __shared__ float hid[32];

    int start = starts[g];
    int cnt = counts[g];
    if (cnt > SORTN) cnt = SORTN;
    int kk = cnt < K_POOL ? cnt : K_POOL;

    // build sort keys: (val desc, idx asc) -> ascending u64 sort
    for (int i = tid; i < SORTN; i += 256) {
        unsigned long long kv;
        if (i < cnt) {
            float v = feat[(size_t)(start + i) * D_TOT + (D_TOT - 1)];
            unsigned uo = __float_as_uint(v);
            uo ^= (unsigned)((int)uo >> 31) | 0x80000000u;    // order-preserving map
            kv = ((unsigned long long)(~uo) << 32) | (unsigned)i;
        } else {
            kv = 0xFFFFFFFFFFFFFFFFull;                       // pad sorts last
        }
        keys[i] = kv;
    }
    __syncthreads();

    // bitonic sort, SORTN elems, 256 threads
    for (int sz = 2; sz <= SORTN; sz <<= 1) {
        for (int j = sz >> 1; j > 0; j >>= 1) {
            for (int q = tid; q < SORTN; q += 256) {
                int l = q ^ j;
                if (l > q) {
                    bool asc = ((q & sz) == 0);
                    unsigned long long a = keys[q], bb = keys[l];
                    if ((a > bb) == asc) { keys[q] = bb; keys[l] = a; }
                }
            }
            __syncthreads();
        }
    }

    // gather pooled rows (zero-pad)
    float* pf = &pooled[0][0];
    for (int t = tid; t < K_POOL * D_TOT; t += 256) pf[t] = 0.f;
    __syncthreads();
    for (int t = tid; t < kk * D_TOT; t += 256) {
        int r = t / D_TOT, c = t - r * D_TOT;
        int idx = (int)(keys[r] & 0xFFFFFFFFull);
        pf[t] = feat[(size_t)(start + idx) * D_TOT + c];
    }
    __syncthreads();

    // conv1: kernel=stride=97 -> per-row dense 97->16, relu
    for (int t = tid; t < 16 * K_POOL; t += 256) {
        int o = t / K_POOL, p = t - o * K_POOL;
        float a = c1b[o];
        const float* w = c1w + o * D_TOT;
        const float* pr = &pooled[p][0];
#pragma unroll 1
        for (int c = 0; c < D_TOT; ++c) a += pr[c] * w[c];
        y[o][p] = fmaxf(a, 0.f);
    }
    __syncthreads();

    for (int t = tid; t < 16 * 15; t += 256) {
        int o = t / 15, p = t - o * 15;
        z[o][p] = fmaxf(y[o][2 * p], y[o][2 * p + 1]);
    }
    __syncthreads();

    // conv2: 16->32 channels, kernel 5, relu; u layout [q*11+p]
    for (int t = tid; t < 32 * 11; t += 256) {
        int q = t / 11, p = t - q * 11;
        float a = c2b[q];
        const float* w = c2w + q * 16 * 5;
#pragma unroll 1
        for (int c = 0; c < 16; ++c) {
#pragma unroll
            for (int j = 0; j < 5; ++j) a += z[c][p + j] * w[c * 5 + j];
        }
        u[t] = fmaxf(a, 0.f);
    }
    __syncthreads();

    // mlp1: 352 -> 32 relu, 8 partial groups of 44 inputs
    {
        int grp = tid >> 5, o = tid & 31;
        float a = 0.f;
        int i0 = grp * 44;
#pragma unroll 1
        for (int i = i0; i < i0 + 44; ++i) a += u[i] * m1w[i * 32 + o];
        pm[tid] = a;
    }
    __syncthreads();
    if (tid < 32) {
        float a = m1b[tid];
#pragma unroll
        for (int gg = 0; gg < 8; ++gg) a += pm[tid + 32 * gg];
        hid[tid] = fmaxf(a, 0.f);
    }
    __syncthreads();

    if (tid == 0) {
        float a = m2b[0];
#pragma unroll
        for (int m = 0; m < 32; ++m) a += hid[m] * m2w[m];
        out[g] = a;
    }
}

// ---------------- launch ----------------
extern "C" void kernel_launch(void* const* d_in, const int* in_sizes, int n_in,
                              void* d_out, int out_size, void* d_ws, size_t ws_size,
                              hipStream_t stream) {
    const float* x    = (const float*)d_in[0];
    const int*   ei   = (const int*)d_in[1];
    const int*   batch= (const int*)d_in[2];
    const float* W0   = (const float*)d_in[3];
    const float* b0   = (const float*)d_in[4];
    const float* W1   = (const float*)d_in[5];
    const float* b1   = (const float*)d_in[6];
    const float* W2   = (const float*)d_in[7];
    const float* b2   = (const float*)d_in[8];
    const float* W3   = (const float*)d_in[9];
    const float* b3   = (const float*)d_in[10];
    const float* c1w  = (const float*)d_in[11];
    const float* c1b  = (const float*)d_in[12];
    const float* c2w  = (const float*)d_in[13];
    const float* c2b  = (const float*)d_in[14];
    const float* m1w  = (const float*)d_in[15];
    const float* m1b  = (const float*)d_in[16];
    const float* m2w  = (const float*)d_in[17];
    const float* m2b  = (const float*)d_in[18];

    const int n = in_sizes[0] / 20;
    const int E = in_sizes[1] / 2;
    const int G = out_size;
    const int* srcv = ei;
    const int* dstv = ei + E;
    const int B = (n + BSIZE - 1) >> BSHIFT;
    const int nE4 = (E + 4095) / 4096;
    const int nE8 = (E + 8191) / 8192;

    char* ws = (char*)d_ws;
    float* feat    = (float*)ws;  ws += (size_t)n * D_TOT * sizeof(float);
    float* gbuf    = (float*)ws;  ws += (size_t)n * 32 * sizeof(float);
    int*   ssrc    = (int*)ws;    ws += (size_t)E * sizeof(int);
    unsigned* bpk  = (unsigned*)ws; ws += (size_t)E * sizeof(unsigned);
    int*   rowstart= (int*)ws;    ws += (size_t)n * sizeof(int);
    int*   deg     = (int*)ws;    ws += (size_t)n * sizeof(int);
    float* dis     = (float*)ws;  ws += (size_t)n * sizeof(float);
    int*   counts  = (int*)ws;    ws += (size_t)G * sizeof(int);
    int*   startsb = (int*)ws;    ws += (size_t)G * sizeof(int);
    int*   bucketcnt=(int*)ws;    ws += (size_t)MAXB * sizeof(int);
    int*   bstart  = (int*)ws;    ws += (size_t)(MAXB + 1) * sizeof(int);
    int*   bcursor = (int*)ws;    ws += (size_t)MAXB * sizeof(int);

    hipMemsetAsync(counts, 0, (size_t)G * sizeof(int), stream);
    hipMemsetAsync(bucketcnt, 0, (size_t)MAXB * sizeof(int), stream);

    // CSR build (bucketed, no global data atomics; reused by all 4 layers)
    k_bcount<<<nE4, 256, 0, stream>>>(dstv, E, bucketcnt, B);
    k_bscan<<<1, MAXB, 0, stream>>>(bucketcnt, bstart, bcursor, B, E);
    k_part<<<nE8, 256, 0, stream>>>(srcv, dstv, E, B, bcursor, bpk);
    k_fill3<<<B, 256, 0, stream>>>(bpk, bstart, n, B, deg, rowstart, dis, ssrc);

    // per-graph segments
    k_hist<<<(n + 255) / 256, 256, 0, stream>>>(batch, n, counts);
    k_scan2<<<1, 1024, 0, stream>>>(counts, startsb, G);

    const int nt32 = n * 32;
    const int nt8  = n * 8;
    // layer 0: 20 -> 32
    k_transform<20, 32><<<(nt32 + 255) / 256, 256, 0, stream>>>(x, 20, W0, dis, gbuf, n);
    k_gather32<<<(nt8 + 255) / 256, 256, 0, stream>>>(rowstart, deg, ssrc, (const float4*)gbuf, dis, b0, feat, 0, n);
    // layer 1
    k_transform<32, 32><<<(nt32 + 255) / 256, 256, 0, stream>>>(feat + 0, D_TOT, W1, dis, gbuf, n);
    k_gather32<<<(nt8 + 255) / 256, 256, 0, stream>>>(rowstart, deg, ssrc, (const float4*)gbuf, dis, b1, feat, 32, n);
    // layer 2
    k_transform<32, 32><<<(nt32 + 255) / 256, 256, 0, stream>>>(feat + 32, D_TOT, W2, dis, gbuf, n);
    k_gather32<<<(nt8 + 255) / 256, 256, 0, stream>>>(rowstart, deg, ssrc, (const float4*)gbuf, dis, b2, feat, 64, n);
    // layer 3: 32 -> 1 (f32 path, table L2-resident)
    k_transform<32, 1><<<(n + 255) / 256, 256, 0, stream>>>(feat + 64, D_TOT, W3, dis, gbuf, n);
    k_gather1<<<(n + 255) / 256, 256, 0, stream>>>(rowstart, deg, ssrc, gbuf, dis, b3, feat, 96, n);

    // fused sort-pool + CNN + MLP
    k_cnn<<<G, 256, 0, stream>>>(feat, startsb, counts,
                                 c1w, c1b, c2w, c2b, m1w, m1b, m2w, m2b,
                                 (float*)d_out);
}

// Round 7
// 481.947 us; speedup vs baseline: 1.8106x; 1.2787x over previous
//
#include <hip/hip_runtime.h>
#include <math.h>

constexpr int D_TOT = 97;
constexpr int K_POOL = 30;
constexpr int BSHIFT = 10;                 // 1024 nodes per bucket
constexpr int BSIZE  = 1 << BSHIFT;
constexpr int MAXB   = 256;                // max buckets (n < 262144)

// ---------------- bucket histogram (LDS-aggregated) ----------------
__global__ __launch_bounds__(256) void k_bcount(const int* __restrict__ dst, int E,
                                                int* __restrict__ bucketcnt, int B) {
    __shared__ int h[MAXB];
    int t = threadIdx.x;
    for (int i = t; i < MAXB; i += 256) h[i] = 0;
    __syncthreads();
    int e0 = blockIdx.x * 4096;
    int e1 = min(e0 + 4096, E);
    for (int i = e0 + t; i < e1; i += 256)
        atomicAdd(&h[dst[i] >> BSHIFT], 1);
    __syncthreads();
    for (int i = t; i < B; i += 256)
        if (h[i]) atomicAdd(&bucketcnt[i], h[i]);
}

// ---------------- bucket exclusive scan ----------------
__global__ void k_bscan(const int* __restrict__ cnt, int* __restrict__ bstart,
                        int* __restrict__ bcursor, int B, int E) {
    __shared__ int s[MAXB];
    int t = threadIdx.x;          // blockDim = 256
    int mine = (t < B) ? cnt[t] : 0;
    s[t] = mine;
    __syncthreads();
    for (int off = 1; off < MAXB; off <<= 1) {
        int add = (t >= off) ? s[t - off] : 0;
        __syncthreads();
        s[t] += add;
        __syncthreads();
    }
    if (t < B) { int ex = s[t] - mine; bstart[t] = ex; bcursor[t] = ex; }
    if (t == 0) bstart[B] = E;
}

// ---------------- per-graph starts via binary search (batch is sorted) ----------------
__global__ void k_starts(const int* __restrict__ batch, int n, int G,
                         int* __restrict__ starts) {
    int g = blockIdx.x * blockDim.x + threadIdx.x;
    if (g > G) return;
    if (g == G) { starts[G] = n; return; }
    int lo = 0, hi = n;
    while (lo < hi) { int mid = (lo + hi) >> 1; if (batch[mid] < g) lo = mid + 1; else hi = mid; }
    starts[g] = lo;
}

// ---------------- phase 1: partition edges into bucket-contiguous packed array ----------------
__global__ __launch_bounds__(256) void k_part(const int* __restrict__ src,
                                              const int* __restrict__ dst, int E, int B,
                                              int* __restrict__ bcursor,
                                              unsigned* __restrict__ bpk) {
    __shared__ int s_src[4096];
    __shared__ int s_dst[4096];
    __shared__ int hist[MAXB];
    __shared__ int base[MAXB];
    int t = threadIdx.x;
    int e0 = blockIdx.x * 4096;
    int cnt = min(4096, E - e0);
    for (int i = t; i < MAXB; i += 256) hist[i] = 0;
    __syncthreads();
    for (int i = t; i < cnt; i += 256) {
        int d = dst[e0 + i];
        s_src[i] = src[e0 + i];
        s_dst[i] = d;
        atomicAdd(&hist[d >> BSHIFT], 1);
    }
    __syncthreads();
    for (int i = t; i < B; i += 256) {
        int hh = hist[i];
        base[i] = hh ? atomicAdd(&bcursor[i], hh) : 0;
        hist[i] = 0;
    }
    __syncthreads();
    for (int i = t; i < cnt; i += 256) {
        int d = s_dst[i];
        int b = d >> BSHIFT;
        int off = atomicAdd(&hist[b], 1);
        bpk[base[b] + off] = ((unsigned)(d & (BSIZE - 1)) << 18) | (unsigned)s_src[i];
    }
}

// ---------------- phase 2: one block per bucket — LDS count+scan+scatter ----------------
__global__ __launch_bounds__(256) void k_fill3(const unsigned* __restrict__ bpk,
                                               const int* __restrict__ bstart,
                                               int n, int B,
                                               int* __restrict__ deg,
                                               int* __restrict__ rowstart,
                                               float* __restrict__ dis,
                                               int* __restrict__ ssrc) {
    __shared__ int cnt[BSIZE];
    __shared__ int s256[256];
    int b = blockIdx.x;
    int t = threadIdx.x;
    int s0 = bstart[b], s1 = bstart[b + 1];

    for (int i = t; i < BSIZE; i += 256) cnt[i] = 0;
    __syncthreads();
    for (int i = s0 + t; i < s1; i += 256)
        atomicAdd(&cnt[bpk[i] >> 18], 1);
    __syncthreads();

    int c0 = cnt[4 * t], c1 = cnt[4 * t + 1], c2 = cnt[4 * t + 2], c3 = cnt[4 * t + 3];
    int tot = c0 + c1 + c2 + c3;
    s256[t] = tot;
    __syncthreads();
    for (int off = 1; off < 256; off <<= 1) {
        int add = (t >= off) ? s256[t - off] : 0;
        __syncthreads();
        s256[t] += add;
        __syncthreads();
    }
    int g0 = s0 + s256[t] - tot;
    int p0 = g0, p1 = g0 + c0, p2 = p1 + c1, p3 = p2 + c2;

    int node0 = (b << BSHIFT) + 4 * t;
    if (node0 + 0 < n) { rowstart[node0 + 0] = p0; deg[node0 + 0] = c0; dis[node0 + 0] = rsqrtf((float)(c0 + 1)); }
    if (node0 + 1 < n) { rowstart[node0 + 1] = p1; deg[node0 + 1] = c1; dis[node0 + 1] = rsqrtf((float)(c1 + 1)); }
    if (node0 + 2 < n) { rowstart[node0 + 2] = p2; deg[node0 + 2] = c2; dis[node0 + 2] = rsqrtf((float)(c2 + 1)); }
    if (node0 + 3 < n) { rowstart[node0 + 3] = p3; deg[node0 + 3] = c3; dis[node0 + 3] = rsqrtf((float)(c3 + 1)); }

    cnt[4 * t] = p0; cnt[4 * t + 1] = p1; cnt[4 * t + 2] = p2; cnt[4 * t + 3] = p3;
    __syncthreads();

    for (int i = s0 + t; i < s1; i += 256) {
        unsigned pk = bpk[i];
        int pos = atomicAdd(&cnt[pk >> 18], 1);
        ssrc[pos] = (int)(pk & 0x3FFFFu);
    }
}

// ---------------- layer-0 transform: g[i,c] = dis[i] * (x[i,:] @ W0[:,c]) ----------------
__global__ void k_transform0(const float* __restrict__ h,
                             const float* __restrict__ W,
                             const float* __restrict__ dis,
                             float* __restrict__ g, int n) {
    int t = blockIdx.x * blockDim.x + threadIdx.x;
    int i = t / 32, c = t % 32;
    if (i >= n) return;
    const float* hr = h + (size_t)i * 20;
    float a = 0.f;
#pragma unroll
    for (int f = 0; f < 20; ++f) a += hr[f] * W[f * 32 + c];
    g[(size_t)i * 32 + c] = dis[i] * a;
}

// ---------------- CSR gather + finalize + fused next-layer transform ----------------
// MODE 0: epilogue computes gnext[i,0:32] = dis[i]*(h @ Wn[32x32])
// MODE 1: epilogue computes gnext[i]      = dis[i]*(h @ Wn[32])
template<int MODE>
__global__ __launch_bounds__(256) void k_gather32f(
    const int* __restrict__ rowstart, const int* __restrict__ deg,
    const int* __restrict__ ssrc, const float4* __restrict__ g4,
    const float* __restrict__ dis, const float* __restrict__ bias,
    const float* __restrict__ Wn,
    float* __restrict__ feat, int off,
    float* __restrict__ gnext, int n)
{
    __shared__ float hs[32][33];
    __shared__ float wsm[32 * 32];
    int t = blockIdx.x * 256 + threadIdx.x;
    int i = t >> 3, p = t & 7;
    bool valid = (i < n);

    if (MODE == 0) {
        for (int q = threadIdx.x; q < 1024; q += 256) wsm[q] = Wn[q];
    }

    float h0 = 0.f, h1 = 0.f, h2 = 0.f, h3 = 0.f;
    float sc = 0.f;
    if (valid) {
        int r0 = rowstart[i], d = deg[i];
        float4 acc = g4[(size_t)i * 8 + p];   // self-loop term
        int j = 0;
        for (; j + 4 <= d; j += 4) {
            int s0 = ssrc[r0 + j + 0];
            int s1 = ssrc[r0 + j + 1];
            int s2 = ssrc[r0 + j + 2];
            int s3 = ssrc[r0 + j + 3];
            float4 v0 = g4[(size_t)s0 * 8 + p];
            float4 v1 = g4[(size_t)s1 * 8 + p];
            float4 v2 = g4[(size_t)s2 * 8 + p];
            float4 v3 = g4[(size_t)s3 * 8 + p];
            acc.x += (v0.x + v1.x) + (v2.x + v3.x);
            acc.y += (v0.y + v1.y) + (v2.y + v3.y);
            acc.z += (v0.z + v1.z) + (v2.z + v3.z);
            acc.w += (v0.w + v1.w) + (v2.w + v3.w);
        }
        for (; j < d; ++j) {
            int s = ssrc[r0 + j];
            float4 v = g4[(size_t)s * 8 + p];
            acc.x += v.x; acc.y += v.y; acc.z += v.z; acc.w += v.w;
        }
        sc = dis[i];
        h0 = tanhf(sc * acc.x + bias[p * 4 + 0]);
        h1 = tanhf(sc * acc.y + bias[p * 4 + 1]);
        h2 = tanhf(sc * acc.z + bias[p * 4 + 2]);
        h3 = tanhf(sc * acc.w + bias[p * 4 + 3]);
        float* fr = feat + (size_t)i * D_TOT + off + p * 4;
        fr[0] = h0; fr[1] = h1; fr[2] = h2; fr[3] = h3;
    }

    int nl = threadIdx.x >> 3;
    hs[nl][p * 4 + 0] = h0;
    hs[nl][p * 4 + 1] = h1;
    hs[nl][p * 4 + 2] = h2;
    hs[nl][p * 4 + 3] = h3;
    __syncthreads();

    if (MODE == 0) {
        if (valid) {
            float a0 = 0.f, a1 = 0.f, a2 = 0.f, a3 = 0.f;
            const float* hr = hs[nl];
            int c0 = p * 4;
#pragma unroll
            for (int f = 0; f < 32; ++f) {
                float hv = hr[f];
                const float* wr = &wsm[f * 32 + c0];
                a0 += hv * wr[0];
                a1 += hv * wr[1];
                a2 += hv * wr[2];
                a3 += hv * wr[3];
            }
            float4* gn = (float4*)gnext;
            gn[(size_t)i * 8 + p] = make_float4(sc * a0, sc * a1, sc * a2, sc * a3);
        }
    } else {
        if (valid && p == 0) {
            float a = 0.f;
            const float* hr = hs[nl];
#pragma unroll
            for (int f = 0; f < 32; ++f) a += hr[f] * Wn[f];
            gnext[i] = sc * a;
        }
    }
}

// ---------------- CSR gather + finalize, FOUT=1 (f32, table is L2-resident) ----------------
__global__ void k_gather1(const int* __restrict__ rowstart, const int* __restrict__ deg,
                          const int* __restrict__ ssrc, const float* __restrict__ g,
                          const float* __restrict__ dis, const float* __restrict__ b,
                          float* __restrict__ feat, int off, int n) {
    int i = blockIdx.x * blockDim.x + threadIdx.x;
    if (i >= n) return;
    int r0 = rowstart[i], d = deg[i];
    float acc = g[i];
    for (int j = 0; j < d; ++j) acc += g[ssrc[r0 + j]];
    feat[(size_t)i * D_TOT + off] = tanhf(dis[i] * acc + b[0]);
}

// ---------------- fused sort-pool (bitonic) + conv1 + maxpool + conv2 + MLP ----------------
constexpr int SORTN = 512;

__global__ __launch_bounds__(256) void k_cnn(
    const float* __restrict__ feat,
    const int* __restrict__ starts,
    const float* __restrict__ c1w, const float* __restrict__ c1b,
    const float* __restrict__ c2w, const float* __restrict__ c2b,
    const float* __restrict__ m1w, const float* __restrict__ m1b,
    const float* __restrict__ m2w, const float* __restrict__ m2b,
    float* __restrict__ out)
{
    int g = blockIdx.x;
    int tid = threadIdx.x;   // 256

    __shared__ unsigned long long keys[SORTN];
    __shared__ float pooled[K_POOL][D_TOT];
    __shared__ float y[16][K_POOL];
    __shared__ float z[16][15];
    __shared__ float u[352];
    __shared__ float pm[256];
    __shared__ float hid[32];

    int start = starts[g];
    int cnt = starts[g + 1] - start;
    if (cnt > SORTN) cnt = SORTN;
    int kk = cnt < K_POOL ? cnt : K_POOL;

    for (int i = tid; i < SORTN; i += 256) {
        unsigned long long kv;
        if (i < cnt) {
            float v = feat[(size_t)(start + i) * D_TOT + (D_TOT - 1)];
            unsigned uo = __float_as_uint(v);
            uo ^= (unsigned)((int)uo >> 31) | 0x80000000u;
            kv = ((unsigned long long)(~uo) << 32) | (unsigned)i;
        } else {
            kv = 0xFFFFFFFFFFFFFFFFull;
        }
        keys[i] = kv;
    }
    __syncthreads();

    for (int sz = 2; sz <= SORTN; sz <<= 1) {
        for (int j = sz >> 1; j > 0; j >>= 1) {
            for (int q = tid; q < SORTN; q += 256) {
                int l = q ^ j;
                if (l > q) {
                    bool asc = ((q & sz) == 0);
                    unsigned long long a = keys[q], bb = keys[l];
                    if ((a > bb) == asc) { keys[q] = bb; keys[l] = a; }
                }
            }
            __syncthreads();
        }
    }

    float* pf = &pooled[0][0];
    for (int t = tid; t < K_POOL * D_TOT; t += 256) pf[t] = 0.f;
    __syncthreads();
    for (int t = tid; t < kk * D_TOT; t += 256) {
        int r = t / D_TOT, c = t - r * D_TOT;
        int idx = (int)(keys[r] & 0xFFFFFFFFull);
        pf[t] = feat[(size_t)(start + idx) * D_TOT + c];
    }
    __syncthreads();

    for (int t = tid; t < 16 * K_POOL; t += 256) {
        int o = t / K_POOL, p = t - o * K_POOL;
        float a = c1b[o];
        const float* w = c1w + o * D_TOT;
        const float* pr = &pooled[p][0];
#pragma unroll 1
        for (int c = 0; c < D_TOT; ++c) a += pr[c] * w[c];
        y[o][p] = fmaxf(a, 0.f);
    }
    __syncthreads();

    for (int t = tid; t < 16 * 15; t += 256) {
        int o = t / 15, p = t - o * 15;
        z[o][p] = fmaxf(y[o][2 * p], y[o][2 * p + 1]);
    }
    __syncthreads();

    for (int t = tid; t < 32 * 11; t += 256) {
        int q = t / 11, p = t - q * 11;
        float a = c2b[q];
        const float* w = c2w + q * 16 * 5;
#pragma unroll 1
        for (int c = 0; c < 16; ++c) {
#pragma unroll
            for (int j = 0; j < 5; ++j) a += z[c][p + j] * w[c * 5 + j];
        }
        u[t] = fmaxf(a, 0.f);
    }
    __syncthreads();

    {
        int grp = tid >> 5, o = tid & 31;
        float a = 0.f;
        int i0 = grp * 44;
#pragma unroll 1
        for (int i = i0; i < i0 + 44; ++i) a += u[i] * m1w[i * 32 + o];
        pm[tid] = a;
    }
    __syncthreads();
    if (tid < 32) {
        float a = m1b[tid];
#pragma unroll
        for (int gg = 0; gg < 8; ++gg) a += pm[tid + 32 * gg];
        hid[tid] = fmaxf(a, 0.f);
    }
    __syncthreads();

    if (tid == 0) {
        float a = m2b[0];
#pragma unroll
        for (int m = 0; m < 32; ++m) a += hid[m] * m2w[m];
        out[g] = a;
    }
}

// ---------------- launch ----------------
extern "C" void kernel_launch(void* const* d_in, const int* in_sizes, int n_in,
                              void* d_out, int out_size, void* d_ws, size_t ws_size,
                              hipStream_t stream) {
    const float* x    = (const float*)d_in[0];
    const int*   ei   = (const int*)d_in[1];
    const int*   batch= (const int*)d_in[2];
    const float* W0   = (const float*)d_in[3];
    const float* b0   = (const float*)d_in[4];
    const float* W1   = (const float*)d_in[5];
    const float* b1   = (const float*)d_in[6];
    const float* W2   = (const float*)d_in[7];
    const float* b2   = (const float*)d_in[8];
    const float* W3   = (const float*)d_in[9];
    const float* b3   = (const float*)d_in[10];
    const float* c1w  = (const float*)d_in[11];
    const float* c1b  = (const float*)d_in[12];
    const float* c2w  = (const float*)d_in[13];
    const float* c2b  = (const float*)d_in[14];
    const float* m1w  = (const float*)d_in[15];
    const float* m1b  = (const float*)d_in[16];
    const float* m2w  = (const float*)d_in[17];
    const float* m2b  = (const float*)d_in[18];

    const int n = in_sizes[0] / 20;
    const int E = in_sizes[1] / 2;
    const int G = out_size;
    const int* srcv = ei;
    const int* dstv = ei + E;
    const int B = (n + BSIZE - 1) >> BSHIFT;
    const int nE4 = (E + 4095) / 4096;

    char* ws = (char*)d_ws;
    float* feat    = (float*)ws;  ws += (size_t)n * D_TOT * sizeof(float);
    float* gA      = (float*)ws;  ws += (size_t)n * 32 * sizeof(float);
    float* gB      = (float*)ws;  ws += (size_t)n * 32 * sizeof(float);
    int*   ssrc    = (int*)ws;    ws += (size_t)E * sizeof(int);
    unsigned* bpk  = (unsigned*)ws; ws += (size_t)E * sizeof(unsigned);
    int*   rowstart= (int*)ws;    ws += (size_t)n * sizeof(int);
    int*   deg     = (int*)ws;    ws += (size_t)n * sizeof(int);
    float* dis     = (float*)ws;  ws += (size_t)n * sizeof(float);
    int*   startsb = (int*)ws;    ws += (size_t)(G + 1) * sizeof(int);
    int*   bucketcnt=(int*)ws;    ws += (size_t)MAXB * sizeof(int);
    int*   bstart  = (int*)ws;    ws += (size_t)(MAXB + 1) * sizeof(int);
    int*   bcursor = (int*)ws;    ws += (size_t)MAXB * sizeof(int);
    float* g1      = (float*)bpk;  // alias: bpk dead after CSR build

    hipMemsetAsync(bucketcnt, 0, (size_t)MAXB * sizeof(int), stream);

    // CSR build (bucketed, no global data atomics; reused by all 4 layers)
    k_bcount<<<nE4, 256, 0, stream>>>(dstv, E, bucketcnt, B);
    k_bscan<<<1, MAXB, 0, stream>>>(bucketcnt, bstart, bcursor, B, E);
    k_part<<<nE4, 256, 0, stream>>>(srcv, dstv, E, B, bcursor, bpk);
    k_fill3<<<B, 256, 0, stream>>>(bpk, bstart, n, B, deg, rowstart, dis, ssrc);

    // per-graph starts (batch sorted -> binary search)
    k_starts<<<(G + 256) / 256, 256, 0, stream>>>(batch, n, G, startsb);

    const int nt32 = n * 32;
    const int nb8  = (n * 8 + 255) / 256;
    // layer 0 transform: 20 -> 32
    k_transform0<<<(nt32 + 255) / 256, 256, 0, stream>>>(x, W0, dis, gA, n);
    // layer 0 gather + fused transform W1 -> gB
    k_gather32f<0><<<nb8, 256, 0, stream>>>(rowstart, deg, ssrc, (const float4*)gA, dis, b0, W1, feat, 0, gB, n);
    // layer 1 gather + fused transform W2 -> gA
    k_gather32f<0><<<nb8, 256, 0, stream>>>(rowstart, deg, ssrc, (const float4*)gB, dis, b1, W2, feat, 32, gA, n);
    // layer 2 gather + fused scalar transform W3 -> g1
    k_gather32f<1><<<nb8, 256, 0, stream>>>(rowstart, deg, ssrc, (const float4*)gA, dis, b2, W3, feat, 64, g1, n);
    // layer 3 gather (scalar)
    k_gather1<<<(n + 255) / 256, 256, 0, stream>>>(rowstart, deg, ssrc, g1, dis, b3, feat, 96, n);

    // fused sort-pool + CNN + MLP
    k_cnn<<<G, 256, 0, stream>>>(feat, startsb,
                                 c1w, c1b, c2w, c2b, m1w, m1b, m2w, m2b,
                                 (float*)d_out);
}